// Round 6
// baseline (221.848 us; speedup 1.0000x reference)
//
#include <hip/hip_runtime.h>

#define N_NODES 50000
#define N_EDGES 800000
#define N_CEDGES 200000
#define D 128
#define CAP_M 64
#define CAP_C 32

typedef short s16x4 __attribute__((ext_vector_type(4)));
typedef short s16x8 __attribute__((ext_vector_type(8)));
typedef float f32x4 __attribute__((ext_vector_type(4)));
typedef __bf16 bf16x8 __attribute__((ext_vector_type(8)));
typedef int i32x4 __attribute__((ext_vector_type(4)));

__device__ __forceinline__ unsigned short f2bf(float f) {
    // round-to-nearest-even f32 -> bf16 (finite inputs only)
    unsigned int u = __builtin_bit_cast(unsigned int, f);
    u = u + 0x7fffu + ((u >> 16) & 1u);
    return (unsigned short)(u >> 16);
}

__device__ __forceinline__ f32x4 ntload(const float* p) {
    return __builtin_nontemporal_load((const f32x4*)p);
}

// ---------------- slotted-CSR fill + weight pre-pack ----------------
// One atomic per edge; edge id goes straight to its node's slot array.
// Degrees are Poisson(16)/Poisson(4): max over 50k nodes ~45/~20, so CAP
// 64/32 has enormous margin.
// Tail blocks (977..1008) pack W1/W2 into MFMA B-fragment order:
// lane l supplies B[k=ks*32+(l>>4)*8+j][n=nt*16+(l&15)], j=0..7.
__global__ void fill_pack_kernel(const int* __restrict__ rm, const int* __restrict__ rc,
                                 int* __restrict__ cnt_m, int* __restrict__ cnt_c,
                                 int* __restrict__ csr_m, int* __restrict__ csr_c,
                                 const float* __restrict__ W1, const float* __restrict__ W2,
                                 s16x8* __restrict__ wp1, s16x8* __restrict__ wp2) {
    if (blockIdx.x < 977) {
        int t = blockIdx.x * blockDim.x + threadIdx.x;
        if (t < N_EDGES / 4) {
            i32x4 r = *(const i32x4*)(rm + t * 4);
#pragma unroll
            for (int j = 0; j < 4; ++j) {
                int pos = atomicAdd(&cnt_m[r[j]], 1);
                if (pos < CAP_M) csr_m[r[j] * CAP_M + pos] = t * 4 + j;
            }
        } else if (t < N_EDGES / 4 + N_CEDGES / 4) {
            int t2 = t - N_EDGES / 4;
            i32x4 r = *(const i32x4*)(rc + t2 * 4);
#pragma unroll
            for (int j = 0; j < 4; ++j) {
                int pos = atomicAdd(&cnt_c[r[j]], 1);
                if (pos < CAP_C) csr_c[r[j] * CAP_C + pos] = t2 * 4 + j;
            }
        }
    } else {
        int t = (blockIdx.x - 977) * blockDim.x + threadIdx.x;
        if (t < 12 * 8 * 64) {
            int ks = t >> 9, rem = t & 511, nt = rem >> 6, l = rem & 63;
            int kb = ks * 32 + ((l >> 4) * 8), col = nt * 16 + (l & 15);
            s16x8 v;
#pragma unroll
            for (int j = 0; j < 8; ++j) v[j] = (short)f2bf(W1[(size_t)(kb + j) * D + col]);
            wp1[t] = v;
        } else if (t < (12 + 4) * 8 * 64) {
            int t2 = t - 12 * 8 * 64;
            int ks = t2 >> 9, rem = t2 & 511, nt = rem >> 6, l = rem & 63;
            int kb = ks * 32 + ((l >> 4) * 8), col = nt * 16 + (l & 15);
            s16x8 v;
#pragma unroll
            for (int j = 0; j < 8; ++j) v[j] = (short)f2bf(W2[(size_t)(kb + j) * D + col]);
            wp2[t2] = v;
        }
    }
}

// ---------------- gather (scatter_mean, half-wave per node) ----------------
// Each HALF-WAVE owns one node: 32 lanes x 16B = one full 512B edge row per
// instruction; each lane owns its 4-float column chunk end-to-end -> NO
// cross-lane reduce. 2 nodes/wave, 6250 blocks x 8 nodes = 50000 exactly.
// idx loads are INDEPENDENT of the cnt load (uninitialized slots are read
// safely in-bounds; any use is exec-masked). Straight-line predicated body:
// 24 mesh + 8 contact row-slots (~96%/98% coverage at Poisson(16)/(4)) so
// the scheduler can keep up to 32 row-loads in flight per wave; rare
// overflow handled by guarded cleanup loops.
__launch_bounds__(256)
__global__ void gather_kernel(const float* __restrict__ edge_attr,
                              const float* __restrict__ cedge_attr,
                              const int* __restrict__ csr_m, const int* __restrict__ csr_c,
                              const int* __restrict__ cnt_m, const int* __restrict__ cnt_c,
                              unsigned short* __restrict__ aggm, unsigned short* __restrict__ aggc) {
    const int tid = threadIdx.x;
    const int lane = tid & 63;
    const int h = lane >> 5;          // which half-wave (node select)
    const int sub = lane & 31;        // 16B chunk within row
    const int c0 = sub * 4;           // float offset of this lane's chunk
    const int hb = h << 5;            // shfl base for my half
    const int n = blockIdx.x * 8 + (tid >> 6) * 2 + h;   // my half's node

    // independent load chains: counts and slot vectors issue concurrently
    const int idxm = csr_m[n * CAP_M + sub];   // slots 0..31
    const int idxc = csr_c[n * CAP_C + sub];   // slots 0..31 (all of CAP_C)
    const int cntm = cnt_m[n];
    const int cntc = cnt_c[n];
    const int cm = cntm < CAP_M ? cntm : CAP_M;
    const int cc = cntc < CAP_C ? cntc : CAP_C;

    f32x4 A0 = (f32x4)0.f, A1 = (f32x4)0.f, A2 = (f32x4)0.f, A3 = (f32x4)0.f;
    f32x4 A4 = (f32x4)0.f, A5 = (f32x4)0.f, A6 = (f32x4)0.f, A7 = (f32x4)0.f;
    f32x4 C0 = (f32x4)0.f, C1 = (f32x4)0.f, C2 = (f32x4)0.f, C3 = (f32x4)0.f;
    f32x4* Am[8] = {&A0, &A1, &A2, &A3, &A4, &A5, &A6, &A7};
    f32x4* Cm[4] = {&C0, &C1, &C2, &C3};

    // ---- straight-line predicated body: mesh rows 0..23, contact rows 0..7 ----
#pragma unroll
    for (int r = 0; r < 24; ++r) {
        int e = __shfl(idxm, hb + r);
        if (r < cm) *Am[r & 7] += ntload(edge_attr + (size_t)e * D + c0);
    }
#pragma unroll
    for (int r = 0; r < 8; ++r) {
        int e = __shfl(idxc, hb + r);
        if (r < cc) *Cm[r & 3] += ntload(cedge_attr + (size_t)e * D + c0);
    }

    // ---- rare overflow cleanup ----
    if (__any(cm > 24)) {
#pragma unroll
        for (int r = 24; r < 32; ++r) {
            int e = __shfl(idxm, hb + r);
            if (r < cm) A0 += ntload(edge_attr + (size_t)e * D + c0);
        }
        if (__any(cm > 32)) {
            int idxm2 = csr_m[n * CAP_M + 32 + sub];
            for (int r = 32; r < CAP_M && __any(r < cm); ++r) {
                int e = __shfl(idxm2, hb + (r - 32));
                if (r < cm) A1 += ntload(edge_attr + (size_t)e * D + c0);
            }
        }
    }
    if (__any(cc > 8)) {
        for (int r = 8; r < CAP_C && __any(r < cc); ++r) {
            int e = __shfl(idxc, hb + r);
            if (r < cc) C0 += ntload(cedge_attr + (size_t)e * D + c0);
        }
    }

    // ---- means + stores (full 64-lane coalesced: two agg rows per wave) ----
    {
        f32x4 A = ((A0 + A1) + (A2 + A3)) + ((A4 + A5) + (A6 + A7));
        const float inv = 1.0f / fmaxf((float)cntm, 1.0f);
        s16x4 pv;
#pragma unroll
        for (int k = 0; k < 4; ++k) pv[k] = (short)f2bf(A[k] * inv);
        *(s16x4*)(aggm + (size_t)n * D + c0) = pv;
    }
    {
        f32x4 C = (C0 + C1) + (C2 + C3);
        const float inv = 1.0f / fmaxf((float)cntc, 1.0f);
        s16x4 pv;
#pragma unroll
        for (int k = 0; k < 4; ++k) pv[k] = (short)f2bf(C[k] * inv);
        *(s16x4*)(aggc + (size_t)n * D + c0) = pv;
    }
}

// ---------------- fused MLP + LayerNorm (bf16 MFMA) ----------------
// Block = 256 threads (4 waves), 64 nodes. Wave w owns output rows w*16..w*16+15.
// H-tile ALIASES the X-tile (barrier between GEMM1 and H write) -> 50.2 KB LDS.
__launch_bounds__(256, 3)
__global__ void gemm_fused_kernel(const float* __restrict__ node_attr,
                                  const unsigned short* __restrict__ aggm,
                                  const unsigned short* __restrict__ aggc,
                                  const s16x8* __restrict__ wp1,
                                  const s16x8* __restrict__ wp2,
                                  const float* __restrict__ b1,
                                  const float* __restrict__ b2,
                                  const float* __restrict__ gamma,
                                  const float* __restrict__ beta,
                                  float* __restrict__ out) {
    __shared__ short Xl[64 * 392];  // 64 x 384 bf16, stride 392
    short* Hl = Xl;                 // aliased: 64 x 128 bf16, stride 136
    const int tid = threadIdx.x;
    const int lane = tid & 63;
    const int w = tid >> 6;
    const int m0 = blockIdx.x * 64;

    // stage node_attr (f32 -> bf16) into cols 0..127
#pragma unroll
    for (int it = 0; it < 8; ++it) {
        int c = tid + it * 256;          // 64 rows x 32 float4-chunks
        int row = c >> 5, c4 = c & 31;
        float4 v = make_float4(0.f, 0.f, 0.f, 0.f);
        if (m0 + row < N_NODES) v = *(const float4*)(node_attr + (size_t)(m0 + row) * D + c4 * 4);
        s16x4 sv;
        sv[0] = (short)f2bf(v.x); sv[1] = (short)f2bf(v.y);
        sv[2] = (short)f2bf(v.z); sv[3] = (short)f2bf(v.w);
        *(s16x4*)&Xl[row * 392 + c4 * 4] = sv;
    }
    // stage agg_mesh -> cols 128..255, agg_contact -> cols 256..383 (already bf16)
#pragma unroll
    for (int it = 0; it < 4; ++it) {
        int c = tid + it * 256;          // 64 rows x 16 short8-chunks
        int row = c >> 4, c8 = c & 15;
        s16x8 vm = (s16x8)0, vc = (s16x8)0;
        if (m0 + row < N_NODES) {
            vm = *(const s16x8*)(aggm + (size_t)(m0 + row) * D + c8 * 8);
            vc = *(const s16x8*)(aggc + (size_t)(m0 + row) * D + c8 * 8);
        }
        *(s16x8*)&Xl[row * 392 + 128 + c8 * 8] = vm;
        *(s16x8*)&Xl[row * 392 + 256 + c8 * 8] = vc;
    }
    __syncthreads();

    const int rrow = w * 16 + (lane & 15);
    const int kg = (lane >> 4) * 8;

    // GEMM1: [64x384] @ [384x128]
    f32x4 acc[8];
#pragma unroll
    for (int nt = 0; nt < 8; ++nt) acc[nt] = (f32x4)0.0f;
#pragma unroll
    for (int ks = 0; ks < 12; ++ks) {
        s16x8 a = *(const s16x8*)&Xl[rrow * 392 + ks * 32 + kg];
#pragma unroll
        for (int nt = 0; nt < 8; ++nt) {
            s16x8 b = wp1[(ks * 8 + nt) * 64 + lane];
            acc[nt] = __builtin_amdgcn_mfma_f32_16x16x32_bf16(
                __builtin_bit_cast(bf16x8, a), __builtin_bit_cast(bf16x8, b), acc[nt], 0, 0, 0);
        }
    }
    __syncthreads();   // all waves done reading X before H overwrites it (aliased)

    // bias + relu -> Hl (bf16). Wave-local rows; lgkmcnt orders write->read.
#pragma unroll
    for (int nt = 0; nt < 8; ++nt) {
        float bias = b1[nt * 16 + (lane & 15)];
#pragma unroll
        for (int j = 0; j < 4; ++j) {
            float v = fmaxf(acc[nt][j] + bias, 0.0f);
            int r = w * 16 + (lane >> 4) * 4 + j;
            Hl[r * 136 + nt * 16 + (lane & 15)] = (short)f2bf(v);
        }
    }
    // GEMM2: [64x128] @ [128x128]
    f32x4 acc2[8];
#pragma unroll
    for (int nt = 0; nt < 8; ++nt) acc2[nt] = (f32x4)0.0f;
#pragma unroll
    for (int ks = 0; ks < 4; ++ks) {
        s16x8 a = *(const s16x8*)&Hl[rrow * 136 + ks * 32 + kg];
#pragma unroll
        for (int nt = 0; nt < 8; ++nt) {
            s16x8 b = wp2[(ks * 8 + nt) * 64 + lane];
            acc2[nt] = __builtin_amdgcn_mfma_f32_16x16x32_bf16(
                __builtin_bit_cast(bf16x8, a), __builtin_bit_cast(bf16x8, b), acc2[nt], 0, 0, 0);
        }
    }
    // epilogue: +b2, LayerNorm per row (row lives on a 16-lane group, 8 cols/lane)
    float g8[8], be8[8], b28[8];
#pragma unroll
    for (int nt = 0; nt < 8; ++nt) {
        int c = nt * 16 + (lane & 15);
        g8[nt] = gamma[c]; be8[nt] = beta[c]; b28[nt] = b2[c];
    }
#pragma unroll
    for (int j = 0; j < 4; ++j) {
        float vv[8];
        float s = 0.f, qq = 0.f;
#pragma unroll
        for (int nt = 0; nt < 8; ++nt) {
            float v = acc2[nt][j] + b28[nt];
            vv[nt] = v; s += v; qq += v * v;
        }
#pragma unroll
        for (int m = 1; m < 16; m <<= 1) {
            s += __shfl_xor(s, m);
            qq += __shfl_xor(qq, m);
        }
        float mu = s * (1.0f / D);
        float var = qq * (1.0f / D) - mu * mu;
        float rs = rsqrtf(var + 1e-5f);
        int r = m0 + w * 16 + (lane >> 4) * 4 + j;
        if (r < N_NODES) {
#pragma unroll
            for (int nt = 0; nt < 8; ++nt)
                out[(size_t)r * D + nt * 16 + (lane & 15)] = (vv[nt] - mu) * rs * g8[nt] + be8[nt];
        }
    }
}

// ---------------- launch ----------------

extern "C" void kernel_launch(void* const* d_in, const int* in_sizes, int n_in,
                              void* d_out, int out_size, void* d_ws, size_t ws_size,
                              hipStream_t stream) {
    const float* node_attr  = (const float*)d_in[0];
    const float* edge_attr  = (const float*)d_in[1];
    const float* cedge_attr = (const float*)d_in[2];
    const int*   rm         = (const int*)d_in[3];
    const int*   rc         = (const int*)d_in[4];
    const float* W1         = (const float*)d_in[5];
    const float* b1         = (const float*)d_in[6];
    const float* W2         = (const float*)d_in[7];
    const float* b2         = (const float*)d_in[8];
    const float* gamma      = (const float*)d_in[9];
    const float* beta       = (const float*)d_in[10];
    float* out = (float*)d_out;

    char* ws = (char*)d_ws;
    int* cnt_m  = (int*)(ws + 0);            // 50176 ints
    int* cnt_c  = (int*)(ws + 200704);       // 50176 ints
    int* csr_m  = (int*)(ws + 401408);       // 50000*64 ints = 12.8 MB
    int* csr_c  = (int*)(ws + 13201408);     // 50000*32 ints =  6.4 MB
    s16x8* wp1  = (s16x8*)(ws + 19601408);   // 6144 * 16B
    s16x8* wp2  = (s16x8*)(ws + 19699712);   // 2048 * 16B
    unsigned short* aggm = (unsigned short*)(ws + 19732480);   // 50000*128 bf16
    unsigned short* aggc = (unsigned short*)(ws + 32532480);   // 50000*128 bf16
    // total ws use: ~45.3 MB

    // zero slot counters (harness does not re-poison between replays)
    hipMemsetAsync(ws, 0, 401408, stream);

    fill_pack_kernel<<<1009, 256, 0, stream>>>(rm, rc, cnt_m, cnt_c, csr_m, csr_c,
                                               W1, W2, wp1, wp2);
    gather_kernel<<<6250, 256, 0, stream>>>(edge_attr, cedge_attr, csr_m, csr_c,
                                            cnt_m, cnt_c, aggm, aggc);
    gemm_fused_kernel<<<782, 256, 0, stream>>>(node_attr, aggm, aggc,
                                               wp1, wp2, b1, b2, gamma, beta, out);
}

// Round 7
// 212.726 us; speedup vs baseline: 1.0429x; 1.0429x over previous
//
#include <hip/hip_runtime.h>

#define N_NODES 50000
#define N_EDGES 800000
#define N_CEDGES 200000
#define D 128
#define CAP_M 64
#define CAP_C 32

typedef short s16x4 __attribute__((ext_vector_type(4)));
typedef short s16x8 __attribute__((ext_vector_type(8)));
typedef float f32x4 __attribute__((ext_vector_type(4)));
typedef __bf16 bf16x8 __attribute__((ext_vector_type(8)));
typedef int i32x4 __attribute__((ext_vector_type(4)));

__device__ __forceinline__ unsigned short f2bf(float f) {
    // round-to-nearest-even f32 -> bf16 (finite inputs only)
    unsigned int u = __builtin_bit_cast(unsigned int, f);
    u = u + 0x7fffu + ((u >> 16) & 1u);
    return (unsigned short)(u >> 16);
}

__device__ __forceinline__ f32x4 ntload(const float* p) {
    return __builtin_nontemporal_load((const f32x4*)p);
}

// ---------------- slotted-CSR fill + weight pre-pack ----------------
// One atomic per edge; edge id goes straight to its node's slot array.
// Degrees are Poisson(16)/Poisson(4): max over 50k nodes ~45/~20, so CAP
// 64/32 has enormous margin.
// Tail blocks (977..1008) pack W1/W2 into MFMA B-fragment order:
// lane l supplies B[k=ks*32+(l>>4)*8+j][n=nt*16+(l&15)], j=0..7.
__global__ void fill_pack_kernel(const int* __restrict__ rm, const int* __restrict__ rc,
                                 int* __restrict__ cnt_m, int* __restrict__ cnt_c,
                                 int* __restrict__ csr_m, int* __restrict__ csr_c,
                                 const float* __restrict__ W1, const float* __restrict__ W2,
                                 s16x8* __restrict__ wp1, s16x8* __restrict__ wp2) {
    if (blockIdx.x < 977) {
        int t = blockIdx.x * blockDim.x + threadIdx.x;
        if (t < N_EDGES / 4) {
            i32x4 r = *(const i32x4*)(rm + t * 4);
#pragma unroll
            for (int j = 0; j < 4; ++j) {
                int pos = atomicAdd(&cnt_m[r[j]], 1);
                if (pos < CAP_M) csr_m[r[j] * CAP_M + pos] = t * 4 + j;
            }
        } else if (t < N_EDGES / 4 + N_CEDGES / 4) {
            int t2 = t - N_EDGES / 4;
            i32x4 r = *(const i32x4*)(rc + t2 * 4);
#pragma unroll
            for (int j = 0; j < 4; ++j) {
                int pos = atomicAdd(&cnt_c[r[j]], 1);
                if (pos < CAP_C) csr_c[r[j] * CAP_C + pos] = t2 * 4 + j;
            }
        }
    } else {
        int t = (blockIdx.x - 977) * blockDim.x + threadIdx.x;
        if (t < 12 * 8 * 64) {
            int ks = t >> 9, rem = t & 511, nt = rem >> 6, l = rem & 63;
            int kb = ks * 32 + ((l >> 4) * 8), col = nt * 16 + (l & 15);
            s16x8 v;
#pragma unroll
            for (int j = 0; j < 8; ++j) v[j] = (short)f2bf(W1[(size_t)(kb + j) * D + col]);
            wp1[t] = v;
        } else if (t < (12 + 4) * 8 * 64) {
            int t2 = t - 12 * 8 * 64;
            int ks = t2 >> 9, rem = t2 & 511, nt = rem >> 6, l = rem & 63;
            int kb = ks * 32 + ((l >> 4) * 8), col = nt * 16 + (l & 15);
            s16x8 v;
#pragma unroll
            for (int j = 0; j < 8; ++j) v[j] = (short)f2bf(W2[(size_t)(kb + j) * D + col]);
            wp2[t2] = v;
        }
    }
}

// ---------------- gather (scatter_mean as slotted-CSR gather) ----------------
// One wave per node, 50000 independent waves (round-5 structure, best so far).
// Each HALF-wave (32 lanes x 16B CONTIGUOUS) covers a 512B edge row exactly
// once; 8 rows (4KB) in flight per wave. Slot-index loads are UNCLAMPED
// (always in-bounds; slots >= cnt hold garbage but are never selected by the
// batch-guarded shfls) so cnt and idx load chains issue concurrently.
__launch_bounds__(256)
__global__ void gather_kernel(const float* __restrict__ edge_attr,
                              const float* __restrict__ cedge_attr,
                              const int* __restrict__ csr_m, const int* __restrict__ csr_c,
                              const int* __restrict__ cnt_m, const int* __restrict__ cnt_c,
                              unsigned short* __restrict__ aggm, unsigned short* __restrict__ aggc) {
    const int lane = threadIdx.x & 63;
    const int n = blockIdx.x * 4 + (threadIdx.x >> 6);
    if (n >= N_NODES) return;
    const int h = lane >> 5;          // which row of an instruction pair
    const int sub = lane & 31;        // 16B chunk within row
    const int c0 = sub * 4;           // float offset of this lane's chunk

    // independent load chains: counts + both slot vectors issue concurrently
    const int idxm = csr_m[n * CAP_M + lane];          // slots 0..63 (all of CAP_M)
    const int idxc = csr_c[n * CAP_C + sub];           // slots 0..31 (all of CAP_C)
    const int cntm = cnt_m[n];
    const int cntc = cnt_c[n];
    const int cm = cntm < CAP_M ? cntm : CAP_M;
    const int cc = cntc < CAP_C ? cntc : CAP_C;

    // ---- mesh -> aggm ----
    {
        f32x4 A0 = (f32x4)0.f, A1 = (f32x4)0.f, A2 = (f32x4)0.f, A3 = (f32x4)0.f;
        int i = 0;
        for (; i + 8 <= cm; i += 8) {    // 8 rows in flight
            int e0 = __shfl(idxm, i + h);
            int e1 = __shfl(idxm, i + 2 + h);
            int e2 = __shfl(idxm, i + 4 + h);
            int e3 = __shfl(idxm, i + 6 + h);
            A0 += ntload(edge_attr + (size_t)e0 * D + c0);
            A1 += ntload(edge_attr + (size_t)e1 * D + c0);
            A2 += ntload(edge_attr + (size_t)e2 * D + c0);
            A3 += ntload(edge_attr + (size_t)e3 * D + c0);
        }
        if (i + 4 <= cm) {
            int e0 = __shfl(idxm, i + h);
            int e1 = __shfl(idxm, i + 2 + h);
            A0 += ntload(edge_attr + (size_t)e0 * D + c0);
            A1 += ntload(edge_attr + (size_t)e1 * D + c0);
            i += 4;
        }
        if (i + 2 <= cm) {
            int e0 = __shfl(idxm, i + h);
            A2 += ntload(edge_attr + (size_t)e0 * D + c0);
            i += 2;
        }
        if (i < cm) {                    // single row: only half 0 active
            int e0 = __shfl(idxm, i);
            if (h == 0) A3 += ntload(edge_attr + (size_t)e0 * D + c0);
        }
        f32x4 A = (A0 + A1) + (A2 + A3);
#pragma unroll
        for (int k = 0; k < 4; ++k) A[k] += __shfl_xor(A[k], 32);
        const float inv = 1.0f / fmaxf((float)cntm, 1.0f);
        if (lane < 32) {
            s16x4 pv;
#pragma unroll
            for (int k = 0; k < 4; ++k) pv[k] = (short)f2bf(A[k] * inv);
            *(s16x4*)(aggm + (size_t)n * D + c0) = pv;
        }
    }
    // ---- contact -> aggc ----
    {
        f32x4 A0 = (f32x4)0.f, A1 = (f32x4)0.f, A2 = (f32x4)0.f, A3 = (f32x4)0.f;
        int i = 0;
        for (; i + 8 <= cc; i += 8) {
            int e0 = __shfl(idxc, i + h);
            int e1 = __shfl(idxc, i + 2 + h);
            int e2 = __shfl(idxc, i + 4 + h);
            int e3 = __shfl(idxc, i + 6 + h);
            A0 += ntload(cedge_attr + (size_t)e0 * D + c0);
            A1 += ntload(cedge_attr + (size_t)e1 * D + c0);
            A2 += ntload(cedge_attr + (size_t)e2 * D + c0);
            A3 += ntload(cedge_attr + (size_t)e3 * D + c0);
        }
        if (i + 4 <= cc) {
            int e0 = __shfl(idxc, i + h);
            int e1 = __shfl(idxc, i + 2 + h);
            A0 += ntload(cedge_attr + (size_t)e0 * D + c0);
            A1 += ntload(cedge_attr + (size_t)e1 * D + c0);
            i += 4;
        }
        if (i + 2 <= cc) {
            int e0 = __shfl(idxc, i + h);
            A2 += ntload(cedge_attr + (size_t)e0 * D + c0);
            i += 2;
        }
        if (i < cc) {
            int e0 = __shfl(idxc, i);
            if (h == 0) A3 += ntload(cedge_attr + (size_t)e0 * D + c0);
        }
        f32x4 A = (A0 + A1) + (A2 + A3);
#pragma unroll
        for (int k = 0; k < 4; ++k) A[k] += __shfl_xor(A[k], 32);
        const float inv = 1.0f / fmaxf((float)cntc, 1.0f);
        if (lane < 32) {
            s16x4 pv;
#pragma unroll
            for (int k = 0; k < 4; ++k) pv[k] = (short)f2bf(A[k] * inv);
            *(s16x4*)(aggc + (size_t)n * D + c0) = pv;
        }
    }
}

// ---------------- fused MLP + LayerNorm (bf16 MFMA) ----------------
// Block = 256 threads (4 waves), 64 nodes. Wave w owns output rows w*16..w*16+15.
// H-tile ALIASES the X-tile (barrier between GEMM1 and H write) -> 50.2 KB LDS.
__launch_bounds__(256, 3)
__global__ void gemm_fused_kernel(const float* __restrict__ node_attr,
                                  const unsigned short* __restrict__ aggm,
                                  const unsigned short* __restrict__ aggc,
                                  const s16x8* __restrict__ wp1,
                                  const s16x8* __restrict__ wp2,
                                  const float* __restrict__ b1,
                                  const float* __restrict__ b2,
                                  const float* __restrict__ gamma,
                                  const float* __restrict__ beta,
                                  float* __restrict__ out) {
    __shared__ short Xl[64 * 392];  // 64 x 384 bf16, stride 392
    short* Hl = Xl;                 // aliased: 64 x 128 bf16, stride 136
    const int tid = threadIdx.x;
    const int lane = tid & 63;
    const int w = tid >> 6;
    const int m0 = blockIdx.x * 64;

    // stage node_attr (f32 -> bf16) into cols 0..127
#pragma unroll
    for (int it = 0; it < 8; ++it) {
        int c = tid + it * 256;          // 64 rows x 32 float4-chunks
        int row = c >> 5, c4 = c & 31;
        float4 v = make_float4(0.f, 0.f, 0.f, 0.f);
        if (m0 + row < N_NODES) v = *(const float4*)(node_attr + (size_t)(m0 + row) * D + c4 * 4);
        s16x4 sv;
        sv[0] = (short)f2bf(v.x); sv[1] = (short)f2bf(v.y);
        sv[2] = (short)f2bf(v.z); sv[3] = (short)f2bf(v.w);
        *(s16x4*)&Xl[row * 392 + c4 * 4] = sv;
    }
    // stage agg_mesh -> cols 128..255, agg_contact -> cols 256..383 (already bf16)
#pragma unroll
    for (int it = 0; it < 4; ++it) {
        int c = tid + it * 256;          // 64 rows x 16 short8-chunks
        int row = c >> 4, c8 = c & 15;
        s16x8 vm = (s16x8)0, vc = (s16x8)0;
        if (m0 + row < N_NODES) {
            vm = *(const s16x8*)(aggm + (size_t)(m0 + row) * D + c8 * 8);
            vc = *(const s16x8*)(aggc + (size_t)(m0 + row) * D + c8 * 8);
        }
        *(s16x8*)&Xl[row * 392 + 128 + c8 * 8] = vm;
        *(s16x8*)&Xl[row * 392 + 256 + c8 * 8] = vc;
    }
    __syncthreads();

    const int rrow = w * 16 + (lane & 15);
    const int kg = (lane >> 4) * 8;

    // GEMM1: [64x384] @ [384x128]
    f32x4 acc[8];
#pragma unroll
    for (int nt = 0; nt < 8; ++nt) acc[nt] = (f32x4)0.0f;
#pragma unroll
    for (int ks = 0; ks < 12; ++ks) {
        s16x8 a = *(const s16x8*)&Xl[rrow * 392 + ks * 32 + kg];
#pragma unroll
        for (int nt = 0; nt < 8; ++nt) {
            s16x8 b = wp1[(ks * 8 + nt) * 64 + lane];
            acc[nt] = __builtin_amdgcn_mfma_f32_16x16x32_bf16(
                __builtin_bit_cast(bf16x8, a), __builtin_bit_cast(bf16x8, b), acc[nt], 0, 0, 0);
        }
    }
    __syncthreads();   // all waves done reading X before H overwrites it (aliased)

    // bias + relu -> Hl (bf16). Wave-local rows; lgkmcnt orders write->read.
#pragma unroll
    for (int nt = 0; nt < 8; ++nt) {
        float bias = b1[nt * 16 + (lane & 15)];
#pragma unroll
        for (int j = 0; j < 4; ++j) {
            float v = fmaxf(acc[nt][j] + bias, 0.0f);
            int r = w * 16 + (lane >> 4) * 4 + j;
            Hl[r * 136 + nt * 16 + (lane & 15)] = (short)f2bf(v);
        }
    }
    // GEMM2: [64x128] @ [128x128]
    f32x4 acc2[8];
#pragma unroll
    for (int nt = 0; nt < 8; ++nt) acc2[nt] = (f32x4)0.0f;
#pragma unroll
    for (int ks = 0; ks < 4; ++ks) {
        s16x8 a = *(const s16x8*)&Hl[rrow * 136 + ks * 32 + kg];
#pragma unroll
        for (int nt = 0; nt < 8; ++nt) {
            s16x8 b = wp2[(ks * 8 + nt) * 64 + lane];
            acc2[nt] = __builtin_amdgcn_mfma_f32_16x16x32_bf16(
                __builtin_bit_cast(bf16x8, a), __builtin_bit_cast(bf16x8, b), acc2[nt], 0, 0, 0);
        }
    }
    // epilogue: +b2, LayerNorm per row (row lives on a 16-lane group, 8 cols/lane)
    float g8[8], be8[8], b28[8];
#pragma unroll
    for (int nt = 0; nt < 8; ++nt) {
        int c = nt * 16 + (lane & 15);
        g8[nt] = gamma[c]; be8[nt] = beta[c]; b28[nt] = b2[c];
    }
#pragma unroll
    for (int j = 0; j < 4; ++j) {
        float vv[8];
        float s = 0.f, qq = 0.f;
#pragma unroll
        for (int nt = 0; nt < 8; ++nt) {
            float v = acc2[nt][j] + b28[nt];
            vv[nt] = v; s += v; qq += v * v;
        }
#pragma unroll
        for (int m = 1; m < 16; m <<= 1) {
            s += __shfl_xor(s, m);
            qq += __shfl_xor(qq, m);
        }
        float mu = s * (1.0f / D);
        float var = qq * (1.0f / D) - mu * mu;
        float rs = rsqrtf(var + 1e-5f);
        int r = m0 + w * 16 + (lane >> 4) * 4 + j;
        if (r < N_NODES) {
#pragma unroll
            for (int nt = 0; nt < 8; ++nt)
                out[(size_t)r * D + nt * 16 + (lane & 15)] = (vv[nt] - mu) * rs * g8[nt] + be8[nt];
        }
    }
}

// ---------------- launch ----------------

extern "C" void kernel_launch(void* const* d_in, const int* in_sizes, int n_in,
                              void* d_out, int out_size, void* d_ws, size_t ws_size,
                              hipStream_t stream) {
    const float* node_attr  = (const float*)d_in[0];
    const float* edge_attr  = (const float*)d_in[1];
    const float* cedge_attr = (const float*)d_in[2];
    const int*   rm         = (const int*)d_in[3];
    const int*   rc         = (const int*)d_in[4];
    const float* W1         = (const float*)d_in[5];
    const float* b1         = (const float*)d_in[6];
    const float* W2         = (const float*)d_in[7];
    const float* b2         = (const float*)d_in[8];
    const float* gamma      = (const float*)d_in[9];
    const float* beta       = (const float*)d_in[10];
    float* out = (float*)d_out;

    char* ws = (char*)d_ws;
    int* cnt_m  = (int*)(ws + 0);            // 50176 ints
    int* cnt_c  = (int*)(ws + 200704);       // 50176 ints
    int* csr_m  = (int*)(ws + 401408);       // 50000*64 ints = 12.8 MB
    int* csr_c  = (int*)(ws + 13201408);     // 50000*32 ints =  6.4 MB
    s16x8* wp1  = (s16x8*)(ws + 19601408);   // 6144 * 16B
    s16x8* wp2  = (s16x8*)(ws + 19699712);   // 2048 * 16B
    unsigned short* aggm = (unsigned short*)(ws + 19732480);   // 50000*128 bf16
    unsigned short* aggc = (unsigned short*)(ws + 32532480);   // 50000*128 bf16
    // total ws use: ~45.3 MB

    // zero slot counters (harness does not re-poison between replays)
    hipMemsetAsync(ws, 0, 401408, stream);

    fill_pack_kernel<<<1009, 256, 0, stream>>>(rm, rc, cnt_m, cnt_c, csr_m, csr_c,
                                               W1, W2, wp1, wp2);
    gather_kernel<<<12500, 256, 0, stream>>>(edge_attr, cedge_attr, csr_m, csr_c,
                                             cnt_m, cnt_c, aggm, aggc);
    gemm_fused_kernel<<<782, 256, 0, stream>>>(node_attr, aggm, aggc,
                                               wp1, wp2, b1, b2, gamma, beta, out);
}